// Round 1
// baseline (1022.216 us; speedup 1.0000x reference)
//
#include <hip/hip_runtime.h>

// Problem constants (verified against setup_inputs at runtime where possible)
#define NHEADS   32
#define NKVHEADS 8
#define HDIM     128
#define HALF     64   // HDIM/2

// ---------------------------------------------------------------------------
// Kernel 0/1: build inverse slot map in workspace.
// inv[s] = t if slot_mapping[t] == s, else -1.
// Lets the cache-fill kernel skip slots that the scatter kernel overwrites.
// ---------------------------------------------------------------------------
__global__ void init_inv_kernel(int* __restrict__ inv, int num_slots) {
    int i = blockIdx.x * blockDim.x + threadIdx.x;
    if (i < num_slots) inv[i] = -1;
}

__global__ void build_inv_kernel(const int* __restrict__ slot_mapping,
                                 int* __restrict__ inv, int T) {
    int t = blockIdx.x * blockDim.x + threadIdx.x;
    if (t < T) inv[slot_mapping[t]] = t;
}

// ---------------------------------------------------------------------------
// Main fused kernel: one block per token.
//  - threads 0..63 compute cos/sin for the 64 NeoX frequencies into LDS
//  - RoPE q (32 heads) and k (8 heads) with float4 pair loads/stores
//  - pass v through
//  - scatter k_out -> cache[0, slot], v -> cache[1, slot]
// All global accesses are float4 (16B/lane), contiguous in >=256B segments.
// ---------------------------------------------------------------------------
__global__ __launch_bounds__(256) void rope_scatter_kernel(
    const float4* __restrict__ q,        // [T, 1024] in float4 units
    const float4* __restrict__ k,        // [T, 256]
    const float4* __restrict__ v,        // [T, 256]
    const int*    __restrict__ positions,
    const int*    __restrict__ slot_mapping,
    float4* __restrict__ q_out,          // [T, 1024]
    float4* __restrict__ k_out,          // [T, 256]
    float4* __restrict__ v_out,          // [T, 256]
    float4* __restrict__ cache,          // [2, num_slots, 256]
    int num_slots)
{
    const int t   = blockIdx.x;
    const int tid = threadIdx.x;

    __shared__ float cs[HALF];
    __shared__ float sn[HALF];

    if (tid < HALF) {
        // inv_freq[j] = 10000^(-j/64) = exp2(-j * log2(10000)/64)
        const float NEG_L2B_OVER_HALF = -13.287712379549449f / 64.0f; // -log2(10000)/64
        float invf = exp2f((float)tid * NEG_L2B_OVER_HALF);
        float f = (float)positions[t] * invf;
        float s, c;
        sincosf(f, &s, &c);
        cs[tid] = c;
        sn[tid] = s;
    }
    __syncthreads();

    const float4* cs4 = (const float4*)cs;  // 16 float4
    const float4* sn4 = (const float4*)sn;

    const float4* qrow  = q     + (size_t)t * (NHEADS * HDIM / 4);   // 1024
    float4*       qorow = q_out + (size_t)t * (NHEADS * HDIM / 4);
    const float4* krow  = k     + (size_t)t * (NKVHEADS * HDIM / 4); // 256
    float4*       korow = k_out + (size_t)t * (NKVHEADS * HDIM / 4);

    const int slot = slot_mapping[t];
    float4* kcache = cache + (size_t)slot * (NKVHEADS * HDIM / 4);
    float4* vcache = cache + ((size_t)num_slots + slot) * (NKVHEADS * HDIM / 4);

    // Pair-work items: each item = (head, j4) handles float4 x1 (dims j4*4..+3)
    // and float4 x2 (dims 64 + j4*4..+3) of one head.
    // q: 32 heads * 16 = 512 items; k: 8 heads * 16 = 128 items. Total 640.
    for (int item = tid; item < 640; item += 256) {
        const bool isq = item < 512;
        const int  it  = isq ? item : (item - 512);
        const int  h   = it >> 4;
        const int  j4  = it & 15;
        const int  o1i = h * 32 + j4;        // float4 index of x1 within row
        const int  o2i = o1i + 16;           // float4 index of x2

        const float4* src = isq ? qrow : krow;
        float4 x1 = src[o1i];
        float4 x2 = src[o2i];
        float4 c  = cs4[j4];
        float4 s  = sn4[j4];

        float4 o1, o2;
        o1.x = x1.x * c.x - x2.x * s.x;  o2.x = x2.x * c.x + x1.x * s.x;
        o1.y = x1.y * c.y - x2.y * s.y;  o2.y = x2.y * c.y + x1.y * s.y;
        o1.z = x1.z * c.z - x2.z * s.z;  o2.z = x2.z * c.z + x1.z * s.z;
        o1.w = x1.w * c.w - x2.w * s.w;  o2.w = x2.w * c.w + x1.w * s.w;

        if (isq) {
            qorow[o1i] = o1;
            qorow[o2i] = o2;
        } else {
            korow[o1i]  = o1;
            korow[o2i]  = o2;
            kcache[o1i] = o1;
            kcache[o2i] = o2;
        }
    }

    // v passthrough: 256 float4 per token, one per thread.
    {
        const float4* vrow  = v     + (size_t)t * (NKVHEADS * HDIM / 4);
        float4*       vorow = v_out + (size_t)t * (NKVHEADS * HDIM / 4);
        float4 val = vrow[tid];
        vorow[tid]  = val;
        vcache[tid] = val;
    }
}

// ---------------------------------------------------------------------------
// Cache fill: copy input kv_cache -> output cache for slots NOT covered by
// slot_mapping (those were already written by the scatter above).
// One block per slot; 256 threads cover 256 float4 of k-part and v-part each.
// ---------------------------------------------------------------------------
__global__ __launch_bounds__(256) void fill_cache_kernel(
    const float4* __restrict__ kv_in,    // [2, num_slots, 256]
    const int*    __restrict__ inv,
    float4* __restrict__ cache,          // [2, num_slots, 256]
    int num_slots)
{
    const int s = blockIdx.x;
    if (inv[s] >= 0) return;  // slot overwritten by scatter; skip
    const int tid = threadIdx.x;
    const size_t koff = (size_t)s * 256 + tid;
    const size_t voff = (size_t)num_slots * 256 + koff;
    cache[koff] = kv_in[koff];
    cache[voff] = kv_in[voff];
}

// ---------------------------------------------------------------------------
extern "C" void kernel_launch(void* const* d_in, const int* in_sizes, int n_in,
                              void* d_out, int out_size, void* d_ws, size_t ws_size,
                              hipStream_t stream) {
    const float* q        = (const float*)d_in[0];
    const float* k        = (const float*)d_in[1];
    const float* v        = (const float*)d_in[2];
    const float* kv_cache = (const float*)d_in[3];
    const int*   positions    = (const int*)d_in[4];
    const int*   slot_mapping = (const int*)d_in[5];

    const int T         = in_sizes[0] / (NHEADS * HDIM);
    const int num_slots = in_sizes[3] / (2 * NKVHEADS * HDIM);

    float* out   = (float*)d_out;
    float* q_out = out;
    float* k_out = q_out + (size_t)T * NHEADS * HDIM;
    float* v_out = k_out + (size_t)T * NKVHEADS * HDIM;
    float* cache = v_out + (size_t)T * NKVHEADS * HDIM;

    int* inv = (int*)d_ws;  // num_slots ints

    init_inv_kernel<<<(num_slots + 255) / 256, 256, 0, stream>>>(inv, num_slots);
    build_inv_kernel<<<(T + 255) / 256, 256, 0, stream>>>(slot_mapping, inv, T);

    rope_scatter_kernel<<<T, 256, 0, stream>>>(
        (const float4*)q, (const float4*)k, (const float4*)v,
        positions, slot_mapping,
        (float4*)q_out, (float4*)k_out, (float4*)v_out, (float4*)cache,
        num_slots);

    fill_cache_kernel<<<num_slots, 256, 0, stream>>>(
        (const float4*)kv_cache, inv, (float4*)cache, num_slots);
}